// Round 8
// baseline (393.328 us; speedup 1.0000x reference)
//
#include <hip/hip_runtime.h>
#include <hip/hip_bf16.h>
#include <math.h>

#define B_  4
#define S_  2048
#define D_  768
#define H_  12
#define HD_ 64
#define DF_ 3072
#define BS_ (B_*S_)

// 0.125 (hd^-0.5) * log2(e): folded into Q projection so softmax runs in exp2 domain
#define QSCALE 0.18033688011112042f

typedef __attribute__((ext_vector_type(8))) short short8;
typedef __attribute__((ext_vector_type(4))) float f32x4;

__device__ __forceinline__ unsigned short f2b(float f){
    unsigned int x = __float_as_uint(f);
    return (unsigned short)((x + 0x7fffu + ((x >> 16) & 1u)) >> 16);   // RNE
}
__device__ __forceinline__ float b2f(unsigned short u){
    return __uint_as_float(((unsigned int)u) << 16);
}

typedef __attribute__((address_space(1))) void gvoid_t;
typedef __attribute__((address_space(3))) void lvoid_t;
typedef __attribute__((address_space(3))) unsigned char lchar_t;
__device__ __forceinline__ void gload_lds16(const unsigned short* g, unsigned short* l){
    __builtin_amdgcn_global_load_lds((gvoid_t*)g, (lvoid_t*)l, 16, 0, 0);
}
__device__ __forceinline__ unsigned ldsaddr(const void* p){
    return (unsigned)(size_t)(lchar_t*)(lvoid_t*)p;
}
// inline-asm ds_read_b128: bypasses compiler alias analysis so NO conservative
// vmcnt(0) drains get inserted against outstanding global_load_lds (rule #18 —
// must pair with explicit lgkmcnt + sched_barrier(0) before the consuming MFMA).
#define DSR(dst, addr, OFF) \
    asm volatile("ds_read_b128 %0, %1 offset:" #OFF : "=v"(dst) : "v"(addr))

// ---------------------------------------------------------------- merged prep
// grid sections: [0,24576) cvt x | 4*576 DxD transposes | 2304 W1 | 2304 W2 | 9 bias
__global__ __launch_bounds__(256) void prep_kernel(
    const float* __restrict__ x,
    const float* __restrict__ Wq, const float* __restrict__ Wk,
    const float* __restrict__ Wv, const float* __restrict__ Wo,
    const float* __restrict__ W1, const float* __restrict__ W2,
    const float* __restrict__ bq, const float* __restrict__ bk, const float* __restrict__ bv,
    unsigned short* __restrict__ xb, unsigned short* __restrict__ wqkvT,
    unsigned short* __restrict__ woT, unsigned short* __restrict__ w1T,
    unsigned short* __restrict__ w2T, float* __restrict__ bqkv)
{
    const int NCVT = (BS_*D_)/256;         // 24576
    int bid = blockIdx.x;
    if (bid < NCVT){
        int i = bid*256 + threadIdx.x;
        xb[i] = f2b(x[i]);
        return;
    }
    bid -= NCVT;
    __shared__ float t[32][33];
    const float* src; unsigned short* dst; int K, N, bx, by;
    if (bid < 4*576){
        int wsel = bid / 576, tt = bid % 576;
        bx = tt % 24; by = tt / 24; K = D_; N = D_;
        src = (wsel==0)?Wq:(wsel==1)?Wk:(wsel==2)?Wv:Wo;
        dst = (wsel<3) ? (wqkvT + (size_t)wsel*D_*D_) : woT;
    } else if (bid < 4*576 + 2304){
        int tt = bid - 4*576; bx = tt % 96; by = tt / 96; K = D_; N = DF_; src = W1; dst = w1T;
    } else if (bid < 4*576 + 2*2304){
        int tt = bid - 4*576 - 2304; bx = tt % 24; by = tt / 24; K = DF_; N = D_; src = W2; dst = w2T;
    } else {
        int i = (bid - (4*576 + 2*2304))*256 + threadIdx.x;
        if (i < 3*D_) bqkv[i] = (i < D_) ? bq[i] : (i < 2*D_) ? bk[i-D_] : bv[i-2*D_];
        return;
    }
    int tx = threadIdx.x & 31, ty = threadIdx.x >> 5;
    #pragma unroll
    for (int i = 0; i < 4; ++i)
        t[ty + i*8][tx] = src[(size_t)(by*32 + ty + i*8) * N + bx*32 + tx];
    __syncthreads();
    #pragma unroll
    for (int i = 0; i < 4; ++i)
        dst[(size_t)(bx*32 + ty + i*8) * K + by*32 + tx] = f2b(t[tx][ty + i*8]);
}

// ---------------------------------------------------------------- GEMM (BM=128, BN=64, BK=64)
// C[M,N] = A[M,K] @ Bt[N,K]^T + bias. 4 waves 2Mx2N of 64x32. LDS 24KB -> 6 blocks/CU.
// Round-8 re-tiling (makespan quantization fix): at 4 blocks/CU the BN=128 grids were
// 1152/1536 blocks vs 1024 resident -> partial second wave wasted ~27us per GEMM
// (QKV 61us vs ideal 34). BN=64 doubles block count and 6/CU raises capacity to 1536:
// QKV 2304 = 1.5 waves (short d), FFN1 3072 = exactly 2x1536, Wo/FFN2 1536 = exactly 1x1536.
// Staging via global_load_lds w/ XOR chunk swizzle (contiguous LDS, conflict-free frags).
// act: 0 none, 1 tanh-GELU, 2 QKV-mode. split-K via blockIdx.z (klen per z).
// Bijective XCD swizzle: contiguous tile range per XCD -> L2 locality (T1).
__global__ __launch_bounds__(256, 6) void gemm_tn(
    const unsigned short* __restrict__ A,
    const unsigned short* __restrict__ Bt,
    const float* __restrict__ bias,
    float* __restrict__ Cf,
    unsigned short* __restrict__ Cb,
    unsigned short* __restrict__ vtg,
    int M, int N, int K, int klen, int act)
{
    __shared__ __align__(16) unsigned short As[128*64];
    __shared__ __align__(16) unsigned short Bs[64*64];

    const int tid  = threadIdx.x;
    const int bz   = blockIdx.z;
    const int w    = tid >> 6, lane = tid & 63;
    const int l16  = lane & 15, quad = lane >> 4;
    const int wm   = (w >> 1) * 64, wn = (w & 1) * 32;
    const int kbeg = bz * klen;

    // bijective XCD-aware tile remap (all launches have nwg % 8 == 0):
    // XCD k owns tiles [k*nwg/8, (k+1)*nwg/8) -> contiguous bm rows per XCD L2.
    const int nwg = gridDim.x * gridDim.y;
    int wg = blockIdx.y * gridDim.x + blockIdx.x;
    wg = (wg & 7) * (nwg >> 3) + (wg >> 3);
    const int bn = wg % gridDim.x, bm = wg / gridDim.x;

    const unsigned short* Abase = A  + (size_t)bm * 128 * K;
    const unsigned short* Bbase = Bt + (size_t)bn * 64 * K;

    f32x4 acc[4][2] = {};

    for (int kt = kbeg; kt < kbeg + klen; kt += 64){
        #pragma unroll
        for (int c0 = 0; c0 < 4; ++c0){             // A: 1024 chunks of 16B
            int c = tid + c0 * 256;
            int row = c >> 3, q = c & 7;
            int sw = (q ^ row) & 7;                 // chunk swizzle
            gload_lds16(Abase + (size_t)row * K + kt + sw*8, As + c*8);
        }
        #pragma unroll
        for (int c0 = 0; c0 < 2; ++c0){             // B: 512 chunks of 16B
            int c = tid + c0 * 256;
            int row = c >> 3, q = c & 7;
            int sw = (q ^ row) & 7;
            gload_lds16(Bbase + (size_t)row * K + kt + sw*8, Bs + c*8);
        }
        __syncthreads();

        #pragma unroll
        for (int kc = 0; kc < 2; ++kc){
            short8 af[4], bf[2];
            #pragma unroll
            for (int mi = 0; mi < 4; ++mi)
                af[mi] = *(const short8*)&As[(wm + mi*16 + l16)*64 + (((kc*4 + quad) ^ l16) & 7)*8];
            #pragma unroll
            for (int ni = 0; ni < 2; ++ni)
                bf[ni] = *(const short8*)&Bs[(wn + ni*16 + l16)*64 + (((kc*4 + quad) ^ l16) & 7)*8];
            #pragma unroll
            for (int mi = 0; mi < 4; ++mi)
                #pragma unroll
                for (int ni = 0; ni < 2; ++ni)
                    acc[mi][ni] = __builtin_amdgcn_mfma_f32_16x16x32_bf16(af[mi], bf[ni], acc[mi][ni], 0, 0, 0);
        }
        __syncthreads();
    }

    if (act == 2 && bn >= 24){                      // V columns start at col 1536 = 24*64
        // V cols: vtg[(b*H+h)*64 + d][s] with within-32 slot permutation
        // slot(k) = ((k>>2)&3)*8 + ((k>>4)&1)*4 + (k&3)
        #pragma unroll
        for (int mi = 0; mi < 4; ++mi){
            int rowbase = bm*128 + wm + mi*16 + quad*4;
            int bidx = rowbase >> 11, s0 = rowbase & 2047;
            int sp = (s0 & ~31) | (((s0 >> 2) & 3) << 3) | (((s0 >> 4) & 1) << 2);
            #pragma unroll
            for (int ni = 0; ni < 2; ++ni){
                int col  = bn*64 + wn + ni*16 + l16;
                int hcol = col - 2*D_;
                int hh   = hcol >> 6, dd = hcol & 63;
                float bia = bias ? bias[col] : 0.f;
                unsigned long long pk = 0;
                #pragma unroll
                for (int r = 0; r < 4; ++r)
                    pk |= (unsigned long long)f2b(acc[mi][ni][r] + bia) << (16*r);
                *(unsigned long long*)(vtg + (((size_t)bidx*H_ + hh)*64 + dd)*2048 + sp) = pk;
            }
        }
        return;
    }

    float* Cfz = Cf ? (Cf + (size_t)bz * M * N) : nullptr;
    const bool addb = (bias != nullptr) && (bz == 0);
    #pragma unroll
    for (int mi = 0; mi < 4; ++mi){
        #pragma unroll
        for (int ni = 0; ni < 2; ++ni){
            int col = bn*64 + wn + ni*16 + l16;
            float bia = addb ? bias[col] : 0.f;
            #pragma unroll
            for (int r = 0; r < 4; ++r){
                int row = bm*128 + wm + mi*16 + quad*4 + r;
                float v = acc[mi][ni][r] + bia;
                if (act == 1){
                    // tanh-GELU (max abs err ~3e-4, well within tolerance)
                    float u = v * (0.7978845608028654f + 0.0356774081f * v * v);
                    float e = __builtin_amdgcn_exp2f(u * 2.885390081777927f);  // e^(2u)
                    v = 0.5f * v * (1.f + (1.f - 2.f / (e + 1.f)));
                } else if (act == 2 && col < D_) v *= QSCALE;
                size_t idx = (size_t)row * N + col;
                if (Cfz) Cfz[idx] = v;
                if (Cb) Cb[idx] = f2b(v);
            }
        }
    }
}

// ---------------------------------------------------------------- attention
// S^T = K Q^T; P^T's C-layout regs ARE the PV A-fragment under key-permutation pi;
// V^T stored globally with pi pre-applied. No-max softmax (p = exp2(s) directly).
// 4 waves x 32 q (2 groups of 16); K-frags/V-frags loaded once per granule feed both
// groups. 64-key tiles, double-buffered LDS, single vmcnt(0)+barrier per tile;
// inline-asm ds_read_b128 + counted lgkmcnt + sched_barrier(0) (rule #18).
// Mask fast-path bits hoisted to a prologue bitmask.
__global__ __launch_bounds__(256, 3) void attn_kernel(
    const unsigned short* __restrict__ qkv,
    const unsigned short* __restrict__ vtg,
    const int* __restrict__ mask,
    unsigned short* __restrict__ ctx)
{
    __shared__ __align__(16) unsigned short Kl[2*4096];   // [buf][key 0..63][dchunk ^ (key&7)]
    __shared__ __align__(16) unsigned short Vt[2*4096];   // [buf][d 0..63][slotchunk ^ (d&7)]

    const int tid = threadIdx.x;
    const int bid = blockIdx.x;                  // 768 = 48 heads * 16 qb
    const int hid = bid % 48;                    // same head -> same XCD (bid%8 fixed)
    const int qb  = bid / 48;
    const int h   = hid % H_;
    const int b   = hid / H_;
    const int w   = tid >> 6, lane = tid & 63;   // w in 0..3
    const int l16 = lane & 15, quad = lane >> 4;
    const int q0  = qb * 128 + w * 32;           // wave owns 32 q rows = 2 groups of 16
    const size_t base = (size_t)b * S_;
    const int hoff = h * HD_;

    // Q as B-frag per group: n=q=lane&15, k-slot (quad,j) -> d = kc*32+quad*8+j
    short8 qf[2][2];
    #pragma unroll
    for (int g = 0; g < 2; ++g)
        #pragma unroll
        for (int kc = 0; kc < 2; ++kc)
            qf[g][kc] = *(const short8*)(qkv + (base + q0 + g*16 + l16)*2304 + hoff + kc*32 + quad*8);

    // hoisted mask fast-path bits: bit kt = all 64 keys of tile kt unmasked.
    unsigned okbits = 0;
    for (int kt = 0; kt < 32; ++kt){
        int mv = mask[b*S_ + kt*64 + lane];
        okbits |= (__all(mv != 0) ? (1u << kt) : 0u);
    }

    const unsigned short* vrow = vtg + ((size_t)(b*H_ + h) * 64) * 2048;

    // staging constants: 512 K-chunks + 512 V-chunks of 16B per tile, 4/thread.
    const int rrA  = tid >> 3, slA = tid & 7, swA = (slA ^ rrA) & 7;
    const int koffA = rrA*2304 + hoff + swA*8;
    const int voffA = rrA*2048 + swA*8;
    unsigned short* kd = Kl + tid*8;
    unsigned short* vd = Vt + tid*8;

#define STAGE(_kt, _buf) do{ \
    const unsigned short* kq = qkv + (base + (size_t)(_kt)*64)*2304 + D_; \
    const unsigned short* vq = vrow + (_kt)*64; \
    gload_lds16(kq + koffA,           kd + (_buf)*4096); \
    gload_lds16(kq + koffA + 32*2304, kd + (_buf)*4096 + 2048); \
    gload_lds16(vq + voffA,           vd + (_buf)*4096); \
    gload_lds16(vq + voffA + 32*2048, vd + (_buf)*4096 + 2048); \
}while(0)

    const unsigned fb = (unsigned)(l16*128 + ((quad ^ l16) & 7)*16);
    const unsigned kr0 = ldsaddr(Kl) + fb, kr1 = kr0 ^ 64u;
    const unsigned vr0 = ldsaddr(Vt) + fb, vr1 = vr0 ^ 64u;

    f32x4 o[2][4] = {};
    float l_s[2] = {0.f, 0.f};

    // prologue: tile 0 into buf 0 (also drains Q/mask loads), barrier
    STAGE(0, 0);
    asm volatile("s_waitcnt vmcnt(0)" ::: "memory");
    __builtin_amdgcn_sched_barrier(0);
    __builtin_amdgcn_s_barrier();

    for (int kt = 0; kt < 32; ++kt){
        if (kt + 1 < 32) STAGE(kt + 1, (kt & 1) ^ 1);
        const unsigned rb = (unsigned)(kt & 1) << 13;   // read-buffer byte offset
        const bool allok = (okbits >> kt) & 1u;

        #pragma unroll
        for (int t = 0; t < 2; ++t){
            const unsigned ka0 = kr0 + rb + t*4096, ka1 = kr1 + rb + t*4096;
            const unsigned va  = (t ? vr1 : vr0) + rb;
            short8 kf00, kf01, kf10, kf11, vf[4];
            DSR(kf00, ka0, 0); DSR(kf01, ka0, 2048);
            DSR(kf10, ka1, 0); DSR(kf11, ka1, 2048);
            DSR(vf[0], va, 0); DSR(vf[1], va, 2048); DSR(vf[2], va, 4096); DSR(vf[3], va, 6144);
            asm volatile("s_waitcnt lgkmcnt(4)" ::: "memory");
            __builtin_amdgcn_sched_barrier(0);

            short8 pks[2];
            #pragma unroll
            for (int g = 0; g < 2; ++g){
                f32x4 sf2[2] = {};
                sf2[0] = __builtin_amdgcn_mfma_f32_16x16x32_bf16(kf00, qf[g][0], sf2[0], 0, 0, 0);
                sf2[1] = __builtin_amdgcn_mfma_f32_16x16x32_bf16(kf01, qf[g][0], sf2[1], 0, 0, 0);
                sf2[0] = __builtin_amdgcn_mfma_f32_16x16x32_bf16(kf10, qf[g][1], sf2[0], 0, 0, 0);
                sf2[1] = __builtin_amdgcn_mfma_f32_16x16x32_bf16(kf11, qf[g][1], sf2[1], 0, 0, 0);
                if (!allok){
                    #pragma unroll
                    for (int j = 0; j < 2; ++j)
                        #pragma unroll
                        for (int r = 0; r < 4; ++r)
                            if (mask[b*S_ + kt*64 + (2*t+j)*16 + quad*4 + r] == 0)
                                sf2[j][r] = -1e30f;
                }
                #pragma unroll
                for (int j = 0; j < 2; ++j)
                    #pragma unroll
                    for (int r = 0; r < 4; ++r){
                        float p = __builtin_amdgcn_exp2f(sf2[j][r]);
                        sf2[j][r] = p; l_s[g] += p;
                    }
                union { unsigned int u[4]; short8 s; } pk;
                pk.u[0] = __builtin_amdgcn_perm(__float_as_uint(sf2[0][1]), __float_as_uint(sf2[0][0]), 0x07060302u);
                pk.u[1] = __builtin_amdgcn_perm(__float_as_uint(sf2[0][3]), __float_as_uint(sf2[0][2]), 0x07060302u);
                pk.u[2] = __builtin_amdgcn_perm(__float_as_uint(sf2[1][1]), __float_as_uint(sf2[1][0]), 0x07060302u);
                pk.u[3] = __builtin_amdgcn_perm(__float_as_uint(sf2[1][3]), __float_as_uint(sf2[1][2]), 0x07060302u);
                pks[g] = pk.s;
            }
            asm volatile("s_waitcnt lgkmcnt(0)" ::: "memory");
            __builtin_amdgcn_sched_barrier(0);
            #pragma unroll
            for (int nt = 0; nt < 4; ++nt){
                o[0][nt] = __builtin_amdgcn_mfma_f32_16x16x32_bf16(pks[0], vf[nt], o[0][nt], 0, 0, 0);
                o[1][nt] = __builtin_amdgcn_mfma_f32_16x16x32_bf16(pks[1], vf[nt], o[1][nt], 0, 0, 0);
            }
        }

        asm volatile("s_waitcnt vmcnt(0)" ::: "memory");
        __builtin_amdgcn_sched_barrier(0);
        __builtin_amdgcn_s_barrier();
    }
#undef STAGE

    // per group: reduce l across the 4 quad-copies of each column, normalize + write
    #pragma unroll
    for (int g = 0; g < 2; ++g){
        float ls = l_s[g];
        ls += __shfl_xor(ls, 16);
        ls += __shfl_xor(ls, 32);
        float linv[4];
        #pragma unroll
        for (int r = 0; r < 4; ++r)
            linv[r] = 1.f / __shfl(ls, quad*4 + r);
        #pragma unroll
        for (int nt = 0; nt < 4; ++nt)
            #pragma unroll
            for (int r = 0; r < 4; ++r){
                int qrow = q0 + g*16 + quad*4 + r;
                ctx[(base + qrow)*D_ + hoff + nt*16 + l16] = f2b(o[g][nt][r] * linv[r]);
            }
    }
}

// ---------------------------------------------------------------- LayerNorm (+residual f32 or bf16, up to 2 partials)
__global__ __launch_bounds__(256) void ln_kernel(
    const float* __restrict__ inp, const float* __restrict__ inp2,
    const float* __restrict__ resf, const unsigned short* __restrict__ resb,
    const float* __restrict__ g, const float* __restrict__ be,
    float* __restrict__ outf, unsigned short* __restrict__ outb)
{
    const int row = blockIdx.x;
    const int tid = threadIdx.x;
    const float* ip = inp + (size_t)row * D_;
    const float* ip2 = inp2 ? inp2 + (size_t)row * D_ : nullptr;

    float v[3], s = 0.f, ss = 0.f;
    #pragma unroll
    for (int i = 0; i < 3; ++i){
        int c = tid + i*256;
        float x = ip[c];
        if (ip2) x += ip2[c];
        x += resf ? resf[(size_t)row * D_ + c] : b2f(resb[(size_t)row * D_ + c]);
        v[i] = x; s += x; ss += x * x;
    }
    #pragma unroll
    for (int d = 1; d < 64; d <<= 1){ s += __shfl_xor(s, d); ss += __shfl_xor(ss, d); }
    __shared__ float rs[4], rss[4];
    int w = tid >> 6;
    if ((tid & 63) == 0){ rs[w] = s; rss[w] = ss; }
    __syncthreads();
    s  = rs[0] + rs[1] + rs[2] + rs[3];
    ss = rss[0] + rss[1] + rss[2] + rss[3];
    float mu   = s * (1.f / 768.f);
    float var  = ss * (1.f / 768.f) - mu * mu;
    float rstd = rsqrtf(var + 1e-6f);
    #pragma unroll
    for (int i = 0; i < 3; ++i){
        int c = tid + i*256;
        float y = (v[i] - mu) * rstd * g[c] + be[c];
        if (outf) outf[(size_t)row * D_ + c] = y;
        if (outb) outb[(size_t)row * D_ + c] = f2b(y);
    }
}

// ---------------------------------------------------------------- launch
extern "C" void kernel_launch(void* const* d_in, const int* in_sizes, int n_in,
                              void* d_out, int out_size, void* d_ws, size_t ws_size,
                              hipStream_t stream)
{
    const float* x    = (const float*)d_in[0];
    const int*   mask = (const int*)  d_in[1];
    const float* Wq   = (const float*)d_in[2];
    const float* bq   = (const float*)d_in[3];
    const float* Wk   = (const float*)d_in[4];
    const float* bk   = (const float*)d_in[5];
    const float* Wv   = (const float*)d_in[6];
    const float* bv   = (const float*)d_in[7];
    const float* Wo   = (const float*)d_in[8];
    const float* bo   = (const float*)d_in[9];
    const float* W1   = (const float*)d_in[10];
    const float* b1   = (const float*)d_in[11];
    const float* W2   = (const float*)d_in[12];
    const float* b2   = (const float*)d_in[13];
    const float* g1   = (const float*)d_in[14];
    const float* be1  = (const float*)d_in[15];
    const float* g2   = (const float*)d_in[16];
    const float* be2  = (const float*)d_in[17];
    float* out = (float*)d_out;
    (void)in_sizes; (void)n_in; (void)out_size; (void)ws_size;

    char* ws = (char*)d_ws;
    const size_t n_x = (size_t)BS_ * D_;

    size_t off = 0;
    auto take = [&](size_t bytes){ size_t o = off; off += (bytes + 255) & ~(size_t)255; return o; };
    unsigned short* xb    = (unsigned short*)(ws + take(n_x * 2));   // dead after QKV; reused as hb
    unsigned short* hb    = xb;
    unsigned short* wqkvT = (unsigned short*)(ws + take((size_t)3*D_*D_ * 2));
    unsigned short* woT   = (unsigned short*)(ws + take((size_t)D_*D_ * 2));
    unsigned short* w1T   = (unsigned short*)(ws + take((size_t)D_*DF_ * 2));
    unsigned short* w2T   = (unsigned short*)(ws + take((size_t)D_*DF_ * 2));
    float*          bqkv  = (float*)(ws + take((size_t)3*D_ * 4));
    // qkv [BS][2304] + ctx [BS][768]; region reused by ff1 [BS][3072]
    size_t big = take((size_t)BS_ * 2304 * 2 + n_x * 2);
    unsigned short* qkvb = (unsigned short*)(ws + big);
    unsigned short* ctxb = qkvb + (size_t)BS_ * 2304;
    unsigned short* ff1b = qkvb;
    // fp32 partials (2x): Wo split-K partials, later FFN2 split-K partials
    float* pf32 = (float*)(ws + take(2 * n_x * 4));
    float* mhaf = pf32;
    float* ff2f = pf32;
    unsigned short* vtg = (unsigned short*)(ws + take(n_x * 2));   // [B*H][64][2048] bf16 (pi-permuted)

    // merged prep: cvt x + 6 weight transposes + bias concat in ONE launch
    prep_kernel<<<24576 + 3*2304 + 9, 256, 0, stream>>>(
        x, Wq, Wk, Wv, Wo, W1, W2, bq, bk, bv,
        xb, wqkvT, woT, w1T, w2T, bqkv);

    dim3 blk(256);
    // fused QKV projection: Q scaled, K normal -> qkvb; V -> vtg transposed+permuted
    gemm_tn<<<dim3(36, 64, 1), blk, 0, stream>>>(xb, wqkvT, bqkv, nullptr, qkvb, vtg, BS_, 3*D_, D_, D_, 2);
    // attention (256-thread blocks, 4 waves x 32 q, dbuf 64-key tiles)
    attn_kernel<<<B_ * H_ * (S_/128), 256, 0, stream>>>(qkvb, vtg, mask, ctxb);
    // output projection -> fp32, split-K=2
    gemm_tn<<<dim3(12, 64, 2), blk, 0, stream>>>(ctxb, woT, bo, mhaf, nullptr, nullptr, BS_, D_, D_, D_/2, 0);
    // LN1 (two Wo partials + residual x) -> h bf16 only
    ln_kernel<<<BS_, blk, 0, stream>>>(mhaf, mhaf + n_x, x, nullptr, g1, be1, nullptr, hb);
    // FFN1 + tanh-GELU -> bf16
    gemm_tn<<<dim3(48, 64, 1), blk, 0, stream>>>(hb, w1T, b1, nullptr, ff1b, nullptr, BS_, DF_, D_, D_, 1);
    // FFN2 -> fp32, split-K=2
    gemm_tn<<<dim3(12, 64, 2), blk, 0, stream>>>(ff1b, w2T, b2, ff2f, nullptr, nullptr, BS_, D_, DF_, DF_/2, 0);
    // LN2 -> out (two partials + bf16 residual h)
    ln_kernel<<<BS_, blk, 0, stream>>>(ff2f, ff2f + n_x, nullptr, hb, g2, be2, out, nullptr);
}

// Round 9
// 377.809 us; speedup vs baseline: 1.0411x; 1.0411x over previous
//
#include <hip/hip_runtime.h>
#include <hip/hip_bf16.h>
#include <math.h>

#define B_  4
#define S_  2048
#define D_  768
#define H_  12
#define HD_ 64
#define DF_ 3072
#define BS_ (B_*S_)

// 0.125 (hd^-0.5) * log2(e): folded into Q projection so softmax runs in exp2 domain
#define QSCALE 0.18033688011112042f

typedef __attribute__((ext_vector_type(8))) short short8;
typedef __attribute__((ext_vector_type(4))) float f32x4;

__device__ __forceinline__ unsigned short f2b(float f){
    unsigned int x = __float_as_uint(f);
    return (unsigned short)((x + 0x7fffu + ((x >> 16) & 1u)) >> 16);   // RNE
}
__device__ __forceinline__ float b2f(unsigned short u){
    return __uint_as_float(((unsigned int)u) << 16);
}

typedef __attribute__((address_space(1))) void gvoid_t;
typedef __attribute__((address_space(3))) void lvoid_t;
typedef __attribute__((address_space(3))) unsigned char lchar_t;
__device__ __forceinline__ void gload_lds16(const unsigned short* g, unsigned short* l){
    __builtin_amdgcn_global_load_lds((gvoid_t*)g, (lvoid_t*)l, 16, 0, 0);
}
__device__ __forceinline__ unsigned ldsaddr(const void* p){
    return (unsigned)(size_t)(lchar_t*)(lvoid_t*)p;
}
// inline-asm ds_read_b128: bypasses compiler alias analysis so NO conservative
// vmcnt(0) drains get inserted against outstanding global_load_lds (rule #18 —
// must pair with explicit lgkmcnt + sched_barrier(0) before the consuming MFMA).
#define DSR(dst, addr, OFF) \
    asm volatile("ds_read_b128 %0, %1 offset:" #OFF : "=v"(dst) : "v"(addr))

// ---------------------------------------------------------------- merged prep
// grid sections: [0,24576) cvt x | 4*576 DxD transposes | 2304 W1 | 2304 W2 | 9 bias
__global__ __launch_bounds__(256) void prep_kernel(
    const float* __restrict__ x,
    const float* __restrict__ Wq, const float* __restrict__ Wk,
    const float* __restrict__ Wv, const float* __restrict__ Wo,
    const float* __restrict__ W1, const float* __restrict__ W2,
    const float* __restrict__ bq, const float* __restrict__ bk, const float* __restrict__ bv,
    unsigned short* __restrict__ xb, unsigned short* __restrict__ wqkvT,
    unsigned short* __restrict__ woT, unsigned short* __restrict__ w1T,
    unsigned short* __restrict__ w2T, float* __restrict__ bqkv)
{
    const int NCVT = (BS_*D_)/256;         // 24576
    int bid = blockIdx.x;
    if (bid < NCVT){
        int i = bid*256 + threadIdx.x;
        xb[i] = f2b(x[i]);
        return;
    }
    bid -= NCVT;
    __shared__ float t[32][33];
    const float* src; unsigned short* dst; int K, N, bx, by;
    if (bid < 4*576){
        int wsel = bid / 576, tt = bid % 576;
        bx = tt % 24; by = tt / 24; K = D_; N = D_;
        src = (wsel==0)?Wq:(wsel==1)?Wk:(wsel==2)?Wv:Wo;
        dst = (wsel<3) ? (wqkvT + (size_t)wsel*D_*D_) : woT;
    } else if (bid < 4*576 + 2304){
        int tt = bid - 4*576; bx = tt % 96; by = tt / 96; K = D_; N = DF_; src = W1; dst = w1T;
    } else if (bid < 4*576 + 2*2304){
        int tt = bid - 4*576 - 2304; bx = tt % 24; by = tt / 24; K = DF_; N = D_; src = W2; dst = w2T;
    } else {
        int i = (bid - (4*576 + 2*2304))*256 + threadIdx.x;
        if (i < 3*D_) bqkv[i] = (i < D_) ? bq[i] : (i < 2*D_) ? bk[i-D_] : bv[i-2*D_];
        return;
    }
    int tx = threadIdx.x & 31, ty = threadIdx.x >> 5;
    #pragma unroll
    for (int i = 0; i < 4; ++i)
        t[ty + i*8][tx] = src[(size_t)(by*32 + ty + i*8) * N + bx*32 + tx];
    __syncthreads();
    #pragma unroll
    for (int i = 0; i < 4; ++i)
        dst[(size_t)(bx*32 + ty + i*8) * K + by*32 + tx] = f2b(t[tx][ty + i*8]);
}

// ---------------------------------------------------------------- GEMM (BM=128, BN=64, BK=64)
// C[M,N] = A[M,K] @ Bt[N,K]^T + bias. 4 waves 2Mx2N of 64x32. LDS 24KB -> 6 blocks/CU.
// Round-9: L2-SUPERTILE XCD remap. Round-8's bm-major XCD walk kept the 8 A-rows
// resident (1.57MB) but STREAMED all of B (4.7MB w1T) per bm-row against the ~2.4MB
// of remaining L2 -> B thrashed (FETCH 86MB vs 17 ideal), and the per-kt latency
// chain (gload -> vmcnt drain -> barrier) paid an HBM miss (~900cyc) instead of an
// L2 hit (~250). New walk: XCD k owns bm in [8k,8k+8); within the XCD, bn advances
// in chunks of 12 (B-working 12x98KB=1.15MB) with bm cycling inside each chunk ->
// A panel AND B chunk both L2-resident. Requires gridDim.y==64, gridDim.x%12==0
// (all launches: 36/12/48/12 x 64). Bijective per XCD.
// Staging via global_load_lds w/ XOR chunk swizzle (contiguous LDS, conflict-free frags).
// act: 0 none, 1 tanh-GELU, 2 QKV-mode. split-K via blockIdx.z (klen per z).
__global__ __launch_bounds__(256, 6) void gemm_tn(
    const unsigned short* __restrict__ A,
    const unsigned short* __restrict__ Bt,
    const float* __restrict__ bias,
    float* __restrict__ Cf,
    unsigned short* __restrict__ Cb,
    unsigned short* __restrict__ vtg,
    int M, int N, int K, int klen, int act)
{
    __shared__ __align__(16) unsigned short As[128*64];
    __shared__ __align__(16) unsigned short Bs[64*64];

    const int tid  = threadIdx.x;
    const int bz   = blockIdx.z;
    const int w    = tid >> 6, lane = tid & 63;
    const int l16  = lane & 15, quad = lane >> 4;
    const int wm   = (w >> 1) * 64, wn = (w & 1) * 32;
    const int kbeg = bz * klen;

    // L2-supertile XCD remap (gridDim.y==64, gridDim.x%12==0):
    //   xcd = wg&7 owns bm in [8*xcd, 8*xcd+8); bn walked in chunks of 12.
    int wg = blockIdx.y * gridDim.x + blockIdx.x;
    const int xcd = wg & 7;
    int li = wg >> 3;                       // [0, gridDim.x*8)
    int bchunk = li / 96;                   // 96 = 8 bm x 12 bn per supertile
    int rem = li - bchunk * 96;
    const int bm = xcd * 8 + rem / 12;
    const int bn = bchunk * 12 + rem % 12;

    const unsigned short* Abase = A  + (size_t)bm * 128 * K;
    const unsigned short* Bbase = Bt + (size_t)bn * 64 * K;

    f32x4 acc[4][2] = {};

    for (int kt = kbeg; kt < kbeg + klen; kt += 64){
        #pragma unroll
        for (int c0 = 0; c0 < 4; ++c0){             // A: 1024 chunks of 16B
            int c = tid + c0 * 256;
            int row = c >> 3, q = c & 7;
            int sw = (q ^ row) & 7;                 // chunk swizzle
            gload_lds16(Abase + (size_t)row * K + kt + sw*8, As + c*8);
        }
        #pragma unroll
        for (int c0 = 0; c0 < 2; ++c0){             // B: 512 chunks of 16B
            int c = tid + c0 * 256;
            int row = c >> 3, q = c & 7;
            int sw = (q ^ row) & 7;
            gload_lds16(Bbase + (size_t)row * K + kt + sw*8, Bs + c*8);
        }
        __syncthreads();

        #pragma unroll
        for (int kc = 0; kc < 2; ++kc){
            short8 af[4], bf[2];
            #pragma unroll
            for (int mi = 0; mi < 4; ++mi)
                af[mi] = *(const short8*)&As[(wm + mi*16 + l16)*64 + (((kc*4 + quad) ^ l16) & 7)*8];
            #pragma unroll
            for (int ni = 0; ni < 2; ++ni)
                bf[ni] = *(const short8*)&Bs[(wn + ni*16 + l16)*64 + (((kc*4 + quad) ^ l16) & 7)*8];
            #pragma unroll
            for (int mi = 0; mi < 4; ++mi)
                #pragma unroll
                for (int ni = 0; ni < 2; ++ni)
                    acc[mi][ni] = __builtin_amdgcn_mfma_f32_16x16x32_bf16(af[mi], bf[ni], acc[mi][ni], 0, 0, 0);
        }
        __syncthreads();
    }

    if (act == 2 && bn >= 24){                      // V columns start at col 1536 = 24*64
        // V cols: vtg[(b*H+h)*64 + d][s] with within-32 slot permutation
        // slot(k) = ((k>>2)&3)*8 + ((k>>4)&1)*4 + (k&3)
        #pragma unroll
        for (int mi = 0; mi < 4; ++mi){
            int rowbase = bm*128 + wm + mi*16 + quad*4;
            int bidx = rowbase >> 11, s0 = rowbase & 2047;
            int sp = (s0 & ~31) | (((s0 >> 2) & 3) << 3) | (((s0 >> 4) & 1) << 2);
            #pragma unroll
            for (int ni = 0; ni < 2; ++ni){
                int col  = bn*64 + wn + ni*16 + l16;
                int hcol = col - 2*D_;
                int hh   = hcol >> 6, dd = hcol & 63;
                float bia = bias ? bias[col] : 0.f;
                unsigned long long pk = 0;
                #pragma unroll
                for (int r = 0; r < 4; ++r)
                    pk |= (unsigned long long)f2b(acc[mi][ni][r] + bia) << (16*r);
                *(unsigned long long*)(vtg + (((size_t)bidx*H_ + hh)*64 + dd)*2048 + sp) = pk;
            }
        }
        return;
    }

    float* Cfz = Cf ? (Cf + (size_t)bz * M * N) : nullptr;
    const bool addb = (bias != nullptr) && (bz == 0);
    #pragma unroll
    for (int mi = 0; mi < 4; ++mi){
        #pragma unroll
        for (int ni = 0; ni < 2; ++ni){
            int col = bn*64 + wn + ni*16 + l16;
            float bia = addb ? bias[col] : 0.f;
            #pragma unroll
            for (int r = 0; r < 4; ++r){
                int row = bm*128 + wm + mi*16 + quad*4 + r;
                float v = acc[mi][ni][r] + bia;
                if (act == 1){
                    // tanh-GELU (max abs err ~3e-4, well within tolerance)
                    float u = v * (0.7978845608028654f + 0.0356774081f * v * v);
                    float e = __builtin_amdgcn_exp2f(u * 2.885390081777927f);  // e^(2u)
                    v = 0.5f * v * (1.f + (1.f - 2.f / (e + 1.f)));
                } else if (act == 2 && col < D_) v *= QSCALE;
                size_t idx = (size_t)row * N + col;
                if (Cfz) Cfz[idx] = v;
                if (Cb) Cb[idx] = f2b(v);
            }
        }
    }
}

// ---------------------------------------------------------------- attention
// S^T = K Q^T; P^T's C-layout regs ARE the PV A-fragment under key-permutation pi;
// V^T stored globally with pi pre-applied. No-max softmax (p = exp2(s) directly).
// 4 waves x 32 q (2 groups of 16); K-frags/V-frags loaded once per granule feed both
// groups. 64-key tiles, double-buffered LDS, single vmcnt(0)+barrier per tile;
// inline-asm ds_read_b128 + counted lgkmcnt + sched_barrier(0) (rule #18).
// Mask fast-path bits hoisted to a prologue bitmask.
__global__ __launch_bounds__(256, 3) void attn_kernel(
    const unsigned short* __restrict__ qkv,
    const unsigned short* __restrict__ vtg,
    const int* __restrict__ mask,
    unsigned short* __restrict__ ctx)
{
    __shared__ __align__(16) unsigned short Kl[2*4096];   // [buf][key 0..63][dchunk ^ (key&7)]
    __shared__ __align__(16) unsigned short Vt[2*4096];   // [buf][d 0..63][slotchunk ^ (d&7)]

    const int tid = threadIdx.x;
    const int bid = blockIdx.x;                  // 768 = 48 heads * 16 qb
    const int hid = bid % 48;                    // same head -> same XCD (bid%8 fixed)
    const int qb  = bid / 48;
    const int h   = hid % H_;
    const int b   = hid / H_;
    const int w   = tid >> 6, lane = tid & 63;   // w in 0..3
    const int l16 = lane & 15, quad = lane >> 4;
    const int q0  = qb * 128 + w * 32;           // wave owns 32 q rows = 2 groups of 16
    const size_t base = (size_t)b * S_;
    const int hoff = h * HD_;

    // Q as B-frag per group: n=q=lane&15, k-slot (quad,j) -> d = kc*32+quad*8+j
    short8 qf[2][2];
    #pragma unroll
    for (int g = 0; g < 2; ++g)
        #pragma unroll
        for (int kc = 0; kc < 2; ++kc)
            qf[g][kc] = *(const short8*)(qkv + (base + q0 + g*16 + l16)*2304 + hoff + kc*32 + quad*8);

    // hoisted mask fast-path bits: bit kt = all 64 keys of tile kt unmasked.
    unsigned okbits = 0;
    for (int kt = 0; kt < 32; ++kt){
        int mv = mask[b*S_ + kt*64 + lane];
        okbits |= (__all(mv != 0) ? (1u << kt) : 0u);
    }

    const unsigned short* vrow = vtg + ((size_t)(b*H_ + h) * 64) * 2048;

    // staging constants: 512 K-chunks + 512 V-chunks of 16B per tile, 4/thread.
    const int rrA  = tid >> 3, slA = tid & 7, swA = (slA ^ rrA) & 7;
    const int koffA = rrA*2304 + hoff + swA*8;
    const int voffA = rrA*2048 + swA*8;
    unsigned short* kd = Kl + tid*8;
    unsigned short* vd = Vt + tid*8;

#define STAGE(_kt, _buf) do{ \
    const unsigned short* kq = qkv + (base + (size_t)(_kt)*64)*2304 + D_; \
    const unsigned short* vq = vrow + (_kt)*64; \
    gload_lds16(kq + koffA,           kd + (_buf)*4096); \
    gload_lds16(kq + koffA + 32*2304, kd + (_buf)*4096 + 2048); \
    gload_lds16(vq + voffA,           vd + (_buf)*4096); \
    gload_lds16(vq + voffA + 32*2048, vd + (_buf)*4096 + 2048); \
}while(0)

    const unsigned fb = (unsigned)(l16*128 + ((quad ^ l16) & 7)*16);
    const unsigned kr0 = ldsaddr(Kl) + fb, kr1 = kr0 ^ 64u;
    const unsigned vr0 = ldsaddr(Vt) + fb, vr1 = vr0 ^ 64u;

    f32x4 o[2][4] = {};
    float l_s[2] = {0.f, 0.f};

    // prologue: tile 0 into buf 0 (also drains Q/mask loads), barrier
    STAGE(0, 0);
    asm volatile("s_waitcnt vmcnt(0)" ::: "memory");
    __builtin_amdgcn_sched_barrier(0);
    __builtin_amdgcn_s_barrier();

    for (int kt = 0; kt < 32; ++kt){
        if (kt + 1 < 32) STAGE(kt + 1, (kt & 1) ^ 1);
        const unsigned rb = (unsigned)(kt & 1) << 13;   // read-buffer byte offset
        const bool allok = (okbits >> kt) & 1u;

        #pragma unroll
        for (int t = 0; t < 2; ++t){
            const unsigned ka0 = kr0 + rb + t*4096, ka1 = kr1 + rb + t*4096;
            const unsigned va  = (t ? vr1 : vr0) + rb;
            short8 kf00, kf01, kf10, kf11, vf[4];
            DSR(kf00, ka0, 0); DSR(kf01, ka0, 2048);
            DSR(kf10, ka1, 0); DSR(kf11, ka1, 2048);
            DSR(vf[0], va, 0); DSR(vf[1], va, 2048); DSR(vf[2], va, 4096); DSR(vf[3], va, 6144);
            asm volatile("s_waitcnt lgkmcnt(4)" ::: "memory");
            __builtin_amdgcn_sched_barrier(0);

            short8 pks[2];
            #pragma unroll
            for (int g = 0; g < 2; ++g){
                f32x4 sf2[2] = {};
                sf2[0] = __builtin_amdgcn_mfma_f32_16x16x32_bf16(kf00, qf[g][0], sf2[0], 0, 0, 0);
                sf2[1] = __builtin_amdgcn_mfma_f32_16x16x32_bf16(kf01, qf[g][0], sf2[1], 0, 0, 0);
                sf2[0] = __builtin_amdgcn_mfma_f32_16x16x32_bf16(kf10, qf[g][1], sf2[0], 0, 0, 0);
                sf2[1] = __builtin_amdgcn_mfma_f32_16x16x32_bf16(kf11, qf[g][1], sf2[1], 0, 0, 0);
                if (!allok){
                    #pragma unroll
                    for (int j = 0; j < 2; ++j)
                        #pragma unroll
                        for (int r = 0; r < 4; ++r)
                            if (mask[b*S_ + kt*64 + (2*t+j)*16 + quad*4 + r] == 0)
                                sf2[j][r] = -1e30f;
                }
                #pragma unroll
                for (int j = 0; j < 2; ++j)
                    #pragma unroll
                    for (int r = 0; r < 4; ++r){
                        float p = __builtin_amdgcn_exp2f(sf2[j][r]);
                        sf2[j][r] = p; l_s[g] += p;
                    }
                union { unsigned int u[4]; short8 s; } pk;
                pk.u[0] = __builtin_amdgcn_perm(__float_as_uint(sf2[0][1]), __float_as_uint(sf2[0][0]), 0x07060302u);
                pk.u[1] = __builtin_amdgcn_perm(__float_as_uint(sf2[0][3]), __float_as_uint(sf2[0][2]), 0x07060302u);
                pk.u[2] = __builtin_amdgcn_perm(__float_as_uint(sf2[1][1]), __float_as_uint(sf2[1][0]), 0x07060302u);
                pk.u[3] = __builtin_amdgcn_perm(__float_as_uint(sf2[1][3]), __float_as_uint(sf2[1][2]), 0x07060302u);
                pks[g] = pk.s;
            }
            asm volatile("s_waitcnt lgkmcnt(0)" ::: "memory");
            __builtin_amdgcn_sched_barrier(0);
            #pragma unroll
            for (int nt = 0; nt < 4; ++nt){
                o[0][nt] = __builtin_amdgcn_mfma_f32_16x16x32_bf16(pks[0], vf[nt], o[0][nt], 0, 0, 0);
                o[1][nt] = __builtin_amdgcn_mfma_f32_16x16x32_bf16(pks[1], vf[nt], o[1][nt], 0, 0, 0);
            }
        }

        asm volatile("s_waitcnt vmcnt(0)" ::: "memory");
        __builtin_amdgcn_sched_barrier(0);
        __builtin_amdgcn_s_barrier();
    }
#undef STAGE

    // per group: reduce l across the 4 quad-copies of each column, normalize + write
    #pragma unroll
    for (int g = 0; g < 2; ++g){
        float ls = l_s[g];
        ls += __shfl_xor(ls, 16);
        ls += __shfl_xor(ls, 32);
        float linv[4];
        #pragma unroll
        for (int r = 0; r < 4; ++r)
            linv[r] = 1.f / __shfl(ls, quad*4 + r);
        #pragma unroll
        for (int nt = 0; nt < 4; ++nt)
            #pragma unroll
            for (int r = 0; r < 4; ++r){
                int qrow = q0 + g*16 + quad*4 + r;
                ctx[(base + qrow)*D_ + hoff + nt*16 + l16] = f2b(o[g][nt][r] * linv[r]);
            }
    }
}

// ---------------------------------------------------------------- LayerNorm (+residual f32 or bf16, up to 2 partials)
__global__ __launch_bounds__(256) void ln_kernel(
    const float* __restrict__ inp, const float* __restrict__ inp2,
    const float* __restrict__ resf, const unsigned short* __restrict__ resb,
    const float* __restrict__ g, const float* __restrict__ be,
    float* __restrict__ outf, unsigned short* __restrict__ outb)
{
    const int row = blockIdx.x;
    const int tid = threadIdx.x;
    const float* ip = inp + (size_t)row * D_;
    const float* ip2 = inp2 ? inp2 + (size_t)row * D_ : nullptr;

    float v[3], s = 0.f, ss = 0.f;
    #pragma unroll
    for (int i = 0; i < 3; ++i){
        int c = tid + i*256;
        float x = ip[c];
        if (ip2) x += ip2[c];
        x += resf ? resf[(size_t)row * D_ + c] : b2f(resb[(size_t)row * D_ + c]);
        v[i] = x; s += x; ss += x * x;
    }
    #pragma unroll
    for (int d = 1; d < 64; d <<= 1){ s += __shfl_xor(s, d); ss += __shfl_xor(ss, d); }
    __shared__ float rs[4], rss[4];
    int w = tid >> 6;
    if ((tid & 63) == 0){ rs[w] = s; rss[w] = ss; }
    __syncthreads();
    s  = rs[0] + rs[1] + rs[2] + rs[3];
    ss = rss[0] + rss[1] + rss[2] + rss[3];
    float mu   = s * (1.f / 768.f);
    float var  = ss * (1.f / 768.f) - mu * mu;
    float rstd = rsqrtf(var + 1e-6f);
    #pragma unroll
    for (int i = 0; i < 3; ++i){
        int c = tid + i*256;
        float y = (v[i] - mu) * rstd * g[c] + be[c];
        if (outf) outf[(size_t)row * D_ + c] = y;
        if (outb) outb[(size_t)row * D_ + c] = f2b(y);
    }
}

// ---------------------------------------------------------------- launch
extern "C" void kernel_launch(void* const* d_in, const int* in_sizes, int n_in,
                              void* d_out, int out_size, void* d_ws, size_t ws_size,
                              hipStream_t stream)
{
    const float* x    = (const float*)d_in[0];
    const int*   mask = (const int*)  d_in[1];
    const float* Wq   = (const float*)d_in[2];
    const float* bq   = (const float*)d_in[3];
    const float* Wk   = (const float*)d_in[4];
    const float* bk   = (const float*)d_in[5];
    const float* Wv   = (const float*)d_in[6];
    const float* bv   = (const float*)d_in[7];
    const float* Wo   = (const float*)d_in[8];
    const float* bo   = (const float*)d_in[9];
    const float* W1   = (const float*)d_in[10];
    const float* b1   = (const float*)d_in[11];
    const float* W2   = (const float*)d_in[12];
    const float* b2   = (const float*)d_in[13];
    const float* g1   = (const float*)d_in[14];
    const float* be1  = (const float*)d_in[15];
    const float* g2   = (const float*)d_in[16];
    const float* be2  = (const float*)d_in[17];
    float* out = (float*)d_out;
    (void)in_sizes; (void)n_in; (void)out_size; (void)ws_size;

    char* ws = (char*)d_ws;
    const size_t n_x = (size_t)BS_ * D_;

    size_t off = 0;
    auto take = [&](size_t bytes){ size_t o = off; off += (bytes + 255) & ~(size_t)255; return o; };
    unsigned short* xb    = (unsigned short*)(ws + take(n_x * 2));   // dead after QKV; reused as hb
    unsigned short* hb    = xb;
    unsigned short* wqkvT = (unsigned short*)(ws + take((size_t)3*D_*D_ * 2));
    unsigned short* woT   = (unsigned short*)(ws + take((size_t)D_*D_ * 2));
    unsigned short* w1T   = (unsigned short*)(ws + take((size_t)D_*DF_ * 2));
    unsigned short* w2T   = (unsigned short*)(ws + take((size_t)D_*DF_ * 2));
    float*          bqkv  = (float*)(ws + take((size_t)3*D_ * 4));
    // qkv [BS][2304] + ctx [BS][768]; region reused by ff1 [BS][3072]
    size_t big = take((size_t)BS_ * 2304 * 2 + n_x * 2);
    unsigned short* qkvb = (unsigned short*)(ws + big);
    unsigned short* ctxb = qkvb + (size_t)BS_ * 2304;
    unsigned short* ff1b = qkvb;
    // fp32 partials (2x): Wo split-K partials, later FFN2 split-K partials
    float* pf32 = (float*)(ws + take(2 * n_x * 4));
    float* mhaf = pf32;
    float* ff2f = pf32;
    unsigned short* vtg = (unsigned short*)(ws + take(n_x * 2));   // [B*H][64][2048] bf16 (pi-permuted)

    // merged prep: cvt x + 6 weight transposes + bias concat in ONE launch
    prep_kernel<<<24576 + 3*2304 + 9, 256, 0, stream>>>(
        x, Wq, Wk, Wv, Wo, W1, W2, bq, bk, bv,
        xb, wqkvT, woT, w1T, w2T, bqkv);

    dim3 blk(256);
    // fused QKV projection: Q scaled, K normal -> qkvb; V -> vtg transposed+permuted
    gemm_tn<<<dim3(36, 64, 1), blk, 0, stream>>>(xb, wqkvT, bqkv, nullptr, qkvb, vtg, BS_, 3*D_, D_, D_, 2);
    // attention (256-thread blocks, 4 waves x 32 q, dbuf 64-key tiles)
    attn_kernel<<<B_ * H_ * (S_/128), 256, 0, stream>>>(qkvb, vtg, mask, ctxb);
    // output projection -> fp32, split-K=2
    gemm_tn<<<dim3(12, 64, 2), blk, 0, stream>>>(ctxb, woT, bo, mhaf, nullptr, nullptr, BS_, D_, D_, D_/2, 0);
    // LN1 (two Wo partials + residual x) -> h bf16 only
    ln_kernel<<<BS_, blk, 0, stream>>>(mhaf, mhaf + n_x, x, nullptr, g1, be1, nullptr, hb);
    // FFN1 + tanh-GELU -> bf16
    gemm_tn<<<dim3(48, 64, 1), blk, 0, stream>>>(hb, w1T, b1, nullptr, ff1b, nullptr, BS_, DF_, D_, D_, 1);
    // FFN2 -> fp32, split-K=2
    gemm_tn<<<dim3(12, 64, 2), blk, 0, stream>>>(ff1b, w2T, b2, ff2f, nullptr, nullptr, BS_, D_, DF_, DF_/2, 0);
    // LN2 -> out (two partials + bf16 residual h)
    ln_kernel<<<BS_, blk, 0, stream>>>(ff2f, ff2f + n_x, nullptr, hb, g2, be2, out, nullptr);
}